// Round 2
// baseline (134.637 us; speedup 1.0000x reference)
//
#include <hip/hip_runtime.h>
#include <cstdint>
#include <cstddef>

#define N_PTS 4096
#define KDIM  512
#define NFEAT 5

typedef __attribute__((ext_vector_type(8))) short bf16x8;   // 8 bf16 = 4 VGPRs
typedef __attribute__((ext_vector_type(4))) float f32x4;
typedef uint32_t u32;

// round-to-nearest-even fp32 -> bf16 (inputs finite)
__device__ inline unsigned short f2bf(float f) {
  union { float f; u32 u; } v; v.f = f;
  u32 r = (v.u + 0x7fffu + ((v.u >> 16) & 1u)) >> 16;
  return (unsigned short)r;
}

__device__ inline void bf2f2(u32 u, float& a, float& b) {
  union { u32 u; float f; } x, y;
  x.u = u << 16; y.u = u & 0xffff0000u;
  a = x.f; b = y.f;
}

// async global->LDS, 16B per lane (dest must be wave-uniform base + lane*16)
__device__ inline void load_lds16(const void* g, void* l) {
  __builtin_amdgcn_global_load_lds(
      (const __attribute__((address_space(1))) void*)g,
      (__attribute__((address_space(3))) void*)l, 16, 0, 0);
}

// ---------------------------------------------------------------------------
// Kernel 1: X (fp32) -> bf16 + per-row squared norms
// ---------------------------------------------------------------------------
__global__ __launch_bounds__(256) void prep_kernel(const float* __restrict__ X,
                                                   short* __restrict__ Xb,
                                                   float* __restrict__ sq) {
  const int row = blockIdx.x;
  const int t = threadIdx.x;
  const float2 v = ((const float2*)(X + (size_t)row * KDIM))[t];
  short2 b;
  b.x = (short)f2bf(v.x);
  b.y = (short)f2bf(v.y);
  ((short2*)(Xb + (size_t)row * KDIM))[t] = b;
  float s = v.x * v.x + v.y * v.y;
#pragma unroll
  for (int off = 32; off; off >>= 1) s += __shfl_down(s, off);
  __shared__ float ws[4];
  if ((t & 63) == 0) ws[t >> 6] = s;
  __syncthreads();
  if (t == 0) sq[row] = ws[0] + ws[1] + ws[2] + ws[3];
}

// ---------------------------------------------------------------------------
// Kernel 2 (symmetric): upper-triangular 128x128 tiles only (bm <= bn).
// BK=64, mfma_f32_16x16x32_bf16, global_load_lds width=16.
// Writes D as bf16 into ws (upper tiles only); off-diag block sums count 2x.
// ---------------------------------------------------------------------------
__global__ __launch_bounds__(256, 2) void dist_kernel(
    const short* __restrict__ Xb, const float* __restrict__ sq,
    unsigned short* __restrict__ Dw, float* __restrict__ gsum) {
  const int bm = blockIdx.y, bn = blockIdx.x;
  if (bm > bn) return;

  __shared__ short As[128 * 64];   // 16 KB, row-major [row][k], BK=64
  __shared__ short Bs[128 * 64];   // 16 KB
  __shared__ float red[4];

  const int tid = threadIdx.x;
  const int lane = tid & 63;
  const int wid = tid >> 6;
  const int wave_m = wid >> 1, wave_n = wid & 1;
  const int lhi = lane >> 4, llo = lane & 15;

  f32x4 acc[4][4];
#pragma unroll
  for (int i = 0; i < 4; ++i)
#pragma unroll
    for (int j = 0; j < 4; ++j) acc[i][j] = (f32x4){0.f, 0.f, 0.f, 0.f};

  // staging: thread t loads row (g*32 + t>>3), k-chunk (t&7)*8 -> LDS byte g*4096 + t*16
  const int srow = tid >> 3;         // 0..31
  const int scol = (tid & 7) * 8;    // k element offset
  const size_t ga0 = (size_t)(bm * 128 + srow) * KDIM + scol;
  const size_t gb0 = (size_t)(bn * 128 + srow) * KDIM + scol;

  for (int kt = 0; kt < KDIM / 64; ++kt) {
    const int koff = kt * 64;
#pragma unroll
    for (int g = 0; g < 4; ++g) {
      load_lds16(Xb + ga0 + (size_t)g * 32 * KDIM + koff, (char*)As + g * 4096 + tid * 16);
      load_lds16(Xb + gb0 + (size_t)g * 32 * KDIM + koff, (char*)Bs + g * 4096 + tid * 16);
    }
    __syncthreads();

    bf16x8 a[2][4], b[2][4];
#pragma unroll
    for (int h = 0; h < 2; ++h)
#pragma unroll
      for (int i = 0; i < 4; ++i) {
        a[h][i] = *(const bf16x8*)&As[(wave_m * 64 + i * 16 + llo) * 64 + h * 32 + lhi * 8];
        b[h][i] = *(const bf16x8*)&Bs[(wave_n * 64 + i * 16 + llo) * 64 + h * 32 + lhi * 8];
      }
#pragma unroll
    for (int h = 0; h < 2; ++h)
#pragma unroll
      for (int i = 0; i < 4; ++i)
#pragma unroll
        for (int j = 0; j < 4; ++j)
          acc[i][j] =
              __builtin_amdgcn_mfma_f32_16x16x32_bf16(a[h][i], b[h][j], acc[i][j], 0, 0, 0);
    __syncthreads();
  }

  // epilogue: C/D layout col=lane&15, row=(lane>>4)*4+reg
  float lsum = 0.f;
  const int gi0 = bm * 128 + wave_m * 64;
  const int gj0 = bn * 128 + wave_n * 64;
#pragma unroll
  for (int i = 0; i < 4; ++i) {
#pragma unroll
    for (int r = 0; r < 4; ++r) {
      const int gi = gi0 + i * 16 + lhi * 4 + r;
      const float sqi = sq[gi];
#pragma unroll
      for (int j = 0; j < 4; ++j) {
        const int gj = gj0 + j * 16 + llo;
        float d2 = sqi + sq[gj] - 2.f * acc[i][j][r];
        float dd = sqrtf(fmaxf(d2, 0.f));
        if (gi == gj) dd = 0.f;  // bf16 self-dot noise under sqrt: force exact 0
        Dw[(size_t)gi * N_PTS + gj] = f2bf(dd);
        lsum += dd;
      }
    }
  }
#pragma unroll
  for (int off = 32; off; off >>= 1) lsum += __shfl_down(lsum, off);
  if (lane == 0) red[wid] = lsum;
  __syncthreads();
  if (tid == 0) {
    const float scale = (bm == bn) ? 1.f : 2.f;  // mirror tile counted once
    atomicAdd(gsum, scale * (red[0] + red[1] + red[2] + red[3]));
  }
}

// ---------------------------------------------------------------------------
// Kernel 3 (symmetric): per upper tile, out = sum_f exp(-d/(bw*mult_f));
// direct write coalesced + mirrored tile via padded-LDS transpose.
// ---------------------------------------------------------------------------
__global__ __launch_bounds__(256) void rbf_kernel(
    const unsigned short* __restrict__ Dw, const float* __restrict__ gsum,
    const float* __restrict__ mult, float* __restrict__ out) {
  const int bm = blockIdx.y, bn = blockIdx.x;
  if (bm > bn) return;

  __shared__ float S[32][132];  // 132 = 128+4 pad, keeps 16B alignment, breaks bank stride

  const float bw = *gsum * (1.0f / ((float)N_PTS * (float)(N_PTS - 1)));
  float c[NFEAT];
#pragma unroll
  for (int f = 0; f < NFEAT; ++f) c[f] = -1.0f / (bw * mult[f]);

  const int t = threadIdx.x;
  const int r = t >> 3;           // 0..31 source row within strip
  const int c16 = (t & 7) * 16;   // 16-col segment
  const int gj0 = bn * 128;
  const int gi_base = bm * 128;

  for (int s = 0; s < 4; ++s) {
    const int gi = gi_base + s * 32 + r;
    const unsigned short* src = Dw + (size_t)gi * N_PTS + gj0 + c16;
    const uint4 p0 = *(const uint4*)src;        // 8 bf16
    const uint4 p1 = *(const uint4*)(src + 8);  // 8 bf16

    float v[16];
    bf2f2(p0.x, v[0], v[1]);   bf2f2(p0.y, v[2], v[3]);
    bf2f2(p0.z, v[4], v[5]);   bf2f2(p0.w, v[6], v[7]);
    bf2f2(p1.x, v[8], v[9]);   bf2f2(p1.y, v[10], v[11]);
    bf2f2(p1.z, v[12], v[13]); bf2f2(p1.w, v[14], v[15]);

    float o[16];
#pragma unroll
    for (int e = 0; e < 16; ++e) {
      float a = 0.f;
#pragma unroll
      for (int f = 0; f < NFEAT; ++f) a += __expf(v[e] * c[f]);
      o[e] = a;
    }

    // direct (upper) tile: coalesced float4 rows
    float* drow = out + (size_t)gi * N_PTS + gj0 + c16;
#pragma unroll
    for (int q = 0; q < 4; ++q)
      ((float4*)drow)[q] = (float4){o[q * 4], o[q * 4 + 1], o[q * 4 + 2], o[q * 4 + 3]};

    if (bm != bn) {
      // stage strip into LDS, then write mirrored (lower) tile coalesced
#pragma unroll
      for (int q = 0; q < 4; ++q)
        *(float4*)&S[r][c16 + q * 4] =
            (float4){o[q * 4], o[q * 4 + 1], o[q * 4 + 2], o[q * 4 + 3]};
      __syncthreads();
      const int tb = gi_base + s * 32;
      const int k = t & 7;
#pragma unroll
      for (int p = 0; p < 4; ++p) {
        const int cc = p * 32 + (t >> 3);
        float4 q4;
        q4.x = S[k * 4 + 0][cc];
        q4.y = S[k * 4 + 1][cc];
        q4.z = S[k * 4 + 2][cc];
        q4.w = S[k * 4 + 3][cc];
        *(float4*)&out[(size_t)(gj0 + cc) * N_PTS + tb + k * 4] = q4;
      }
      __syncthreads();
    }
  }
}

extern "C" void kernel_launch(void* const* d_in, const int* in_sizes, int n_in,
                              void* d_out, int out_size, void* d_ws, size_t ws_size,
                              hipStream_t stream) {
  const float* X = (const float*)d_in[0];
  const float* mult = (const float*)d_in[1];
  float* out = (float*)d_out;

  // ws: gsum@0 | sq@1024 (16KB) | Xb@17408 (4MB) | Dw bf16 @4211712 (32MB)
  char* ws = (char*)d_ws;
  float* gsum = (float*)ws;
  float* sq = (float*)(ws + 1024);
  short* Xb = (short*)(ws + 1024 + N_PTS * sizeof(float));
  unsigned short* Dw = (unsigned short*)(ws + 1024 + N_PTS * sizeof(float) +
                                         (size_t)N_PTS * KDIM * sizeof(short));

  hipMemsetAsync(gsum, 0, 256, stream);
  prep_kernel<<<N_PTS, 256, 0, stream>>>(X, Xb, sq);
  dist_kernel<<<dim3(32, 32), 256, 0, stream>>>(Xb, sq, Dw, gsum);
  rbf_kernel<<<dim3(32, 32), 256, 0, stream>>>(Dw, gsum, mult, out);
}